// Round 1
// 394.086 us; speedup vs baseline: 1.1857x; 1.1857x over previous
//
#include <hip/hip_runtime.h>
#include <cstdint>
#include <cstddef>

// Problem constants (DAC RVQ VAE bottleneck)
constexpr int T   = 4096;
constexpr int BB  = 16;
constexpr int D   = 128;   // INPUT_DIM
constexpr int CB  = 1024;  // CODEBOOK_SIZE
constexpr int CD  = 8;     // CODEBOOK_DIM
constexpr int NCB = 9;     // N_CODEBOOKS

constexpr int TBLK = 64;   // columns (t positions) per block
constexpr int NTHR = 256;  // 4 waves

// Output layout (flat f32 concat, reference return order):
//   z_q [16*128*4096] | kl [1] | commit [1] | cbloss [1] | codes [16*9*4096] | latents [16*72*4096]
constexpr size_t OFF_ZQ    = 0;
constexpr size_t OFF_SCAL  = (size_t)BB * D * T;               // 8388608
constexpr size_t OFF_CODES = OFF_SCAL + 3;                     // 8388611
constexpr size_t OFF_LAT   = OFF_CODES + (size_t)BB * NCB * T; // 8978435

// Workspace layout:
//   afr: A-side (codebook) MFMA fragments, bf16 3-term split, 8 term-pair groups
//        [cb][et(64)][kh(2)][lane(64)][4xu32 = 16B]       -> 1.125 MB
//   h2m: -0.5*||cbn||^2 (exact fp32) in D-tile layout
//        [cb][et(64)][lane(64)][4xf32]                    -> 576 KB
constexpr size_t AFR_U32 = (size_t)NCB * 64 * 2 * 64 * 4;  // 294912 u32
constexpr size_t H2M_F32 = (size_t)NCB * 64 * 64 * 4;      // 147456 f32

typedef short bf16x8 __attribute__((ext_vector_type(8)));
typedef float f32x4  __attribute__((ext_vector_type(4)));

__device__ __forceinline__ unsigned short f2bf(float f) {
    unsigned u = __float_as_uint(f);
    return (unsigned short)((u + (((u >> 16) & 1u) + 0x7FFFu)) >> 16);  // RNE
}
__device__ __forceinline__ float bf2f(unsigned short b) {
    return __uint_as_float((unsigned)b << 16);
}

// Term-pair groups g0..g7 across the 64 K-slots (8 dims each):
//   A (codebook) terms: {c0,c1,c2,c0,c1,c0,c2,c1}
//   B (encoding) terms: {e0,e0,e0,e1,e1,e2,e1,e2}
// -> covers all (ci,ej) with i+j<=2 plus (c2,e1),(c1,e2); drops only c2*e2 (~2^-36).
// k-slot -> (group, dim): k = kh*32 + 16*(j>>2) + h*4 + (j&3), h = lane>>4 (16x16x32 frag layout)
//   group = kh*4 + 2*(j>>2) + (h>>1),  dim = (h&1)*4 + (j&3)

// ---------------------------------------------------------------------------
// Prep: normalize codebook rows, exact -h2 into D-layout, 3-term bf16 split
// into A-fragment layout. Zero the scalar accumulators.
// ---------------------------------------------------------------------------
__global__ void prep_kernel(const float* __restrict__ codebook,
                            unsigned* __restrict__ afr,
                            float* __restrict__ h2m,
                            float* __restrict__ scal) {
    int e = blockIdx.x * blockDim.x + threadIdx.x;
    if (e == 0) { scal[0] = 0.f; scal[1] = 0.f; scal[2] = 0.f; }
    if (e >= NCB * CB) return;
    const int i  = e >> 10;
    const int en = e & 1023;
    const int et = en >> 4;
    const int m  = en & 15;

    float v[CD]; float s2 = 0.f;
#pragma unroll
    for (int j = 0; j < CD; ++j) { v[j] = codebook[(size_t)e * CD + j]; s2 = fmaf(v[j], v[j], s2); }
    float inv = 1.0f / fmaxf(sqrtf(s2), 1e-12f);
    float cn[CD]; float c2 = 0.f;
#pragma unroll
    for (int j = 0; j < CD; ++j) { cn[j] = v[j] * inv; c2 = fmaf(cn[j], cn[j], c2); }
    float nh2 = -0.5f * c2;  // exact fp32, negated (used as MFMA C-init)

    // D layout (m89): col=lane&15, row=(lane>>4)*4+reg. Entry row m -> lanes (m>>2)*16+nl, reg m&3.
    {
        size_t base = (((size_t)i * 64 + et) * 64 + (size_t)(m >> 2) * 16) * 4 + (m & 3);
        for (int nl2 = 0; nl2 < 16; ++nl2) h2m[base + (size_t)nl2 * 4] = nh2;
    }

    // 3-term bf16 split, packed u32 pairs (even dim in lo16)
    unsigned pk[3][4];
#pragma unroll
    for (int w = 0; w < 4; ++w) {
        float x0 = cn[2 * w], x1 = cn[2 * w + 1];
        unsigned short a0 = f2bf(x0); float r0 = x0 - bf2f(a0);
        unsigned short a1 = f2bf(r0); float q0 = r0 - bf2f(a1);
        unsigned short a2 = f2bf(q0);
        unsigned short b0 = f2bf(x1); float r1 = x1 - bf2f(b0);
        unsigned short b1 = f2bf(r1); float q1 = r1 - bf2f(b1);
        unsigned short b2 = f2bf(q1);
        pk[0][w] = (unsigned)a0 | ((unsigned)b0 << 16);
        pk[1][w] = (unsigned)a1 | ((unsigned)b1 << 16);
        pk[2][w] = (unsigned)a2 | ((unsigned)b2 << 16);
    }

    const int At[8] = {0, 1, 2, 0, 1, 0, 2, 1};  // A-side term per group
#pragma unroll
    for (int kh = 0; kh < 2; ++kh) {
#pragma unroll
        for (int h = 0; h < 4; ++h) {
            int A1 = At[kh * 4 + (h >> 1)];       // groups for j0-3
            int A2 = At[kh * 4 + 2 + (h >> 1)];   // groups for j4-7
            int dw = (h & 1) * 2;                 // dim offset in u32 words
            size_t off = ((((size_t)i * 64 + et) * 2 + kh) * 64 + (h * 16 + m)) * 4;
            afr[off + 0] = pk[A1][dw];
            afr[off + 1] = pk[A1][dw + 1];
            afr[off + 2] = pk[A2][dw];
            afr[off + 3] = pk[A2][dw + 1];
        }
    }
}

// ---------------------------------------------------------------------------
// Main fused kernel: one block = 64 consecutive t positions of one batch b.
// Search runs on the matrix pipe: per codebook, D = cbn_split · en_split - h2
// via chained mfma_f32_16x16x32_bf16; VALU does only the argmax.
// ---------------------------------------------------------------------------
__global__ __launch_bounds__(NTHR, 4)
void rvq_kernel(const float* __restrict__ x,
                const float* __restrict__ noise,
                const float* __restrict__ in_w,
                const float* __restrict__ in_b,
                const float* __restrict__ codebook,
                const float* __restrict__ out_w,
                const float* __restrict__ out_b,
                const unsigned* __restrict__ afr,
                const float* __restrict__ h2m,
                float* __restrict__ o_zq,
                float* __restrict__ o_scal,
                float* __restrict__ o_codes,
                float* __restrict__ o_lat) {
    __shared__ float    res[D * TBLK];      // res[k][c], 32 KB
    __shared__ float    zen[TBLK * 9];      // raw z_e, col-major stride 9 (2.25 KB)
    __shared__ unsigned es[TBLK * 12];      // split en: [col][3 terms][4xu32] (3 KB)
    __shared__ float    redS[4 * TBLK];     // per-wave best score (1 KB)
    __shared__ int      redI[4 * TBLK];     // per-wave best index (1 KB)
    __shared__ float    redw[8];

    const int tid = threadIdx.x;
    const int c   = tid & 63;            // column for col-parallel phases
    const int s   = tid >> 6;            // wave id
    const int su  = __builtin_amdgcn_readfirstlane(s);
    const int b   = blockIdx.x >> 6;
    const int t0  = (blockIdx.x & 63) << 6;
    const int t   = t0 + c;

    const int l  = tid & 63;             // lane
    const int h  = l >> 4;               // 16-lane group
    const int nl = l & 15;               // position-within-tile

    // ---------------- phase 0: vae_sample -> z into res, local KL ----------
    float kl_local = 0.f;
    {
        const float* xm = x     + (size_t)b * 2 * D * T + (size_t)(su * 32) * T + t;
        const float* xs = xm    + (size_t)D * T;
        const float* nz = noise + (size_t)b * D * T     + (size_t)(su * 32) * T + t;
#pragma unroll 8
        for (int k = 0; k < 32; ++k) {
            float m  = xm[(size_t)k * T];
            float sc = xs[(size_t)k * T];
            float nv = nz[(size_t)k * T];
            float sp  = fmaxf(sc, 0.f) + log1pf(expf(-fabsf(sc)));  // softplus
            float sd  = sp + 1e-4f;
            float var = sd * sd;
            float zv  = fmaf(nv, sd, m);
            res[(su * 32 + k) * TBLK + c] = zv;
            kl_local += m * m + var - logf(var) - 1.0f;
        }
    }

    float loss_local = 0.f;

    // ---------------- RVQ loop over 9 codebooks ----------------------------
    for (int i = 0; i < NCB; ++i) {
        __syncthreads();  // res stable; zen/es free for reuse

        // in_proj: wave computes z_e rows d = su, su+4 for all 64 cols
        {
            const float* w0 = in_w + (size_t)(i * CD + su) * D;   // uniform
            const float* w1 = w0 + 4 * D;
            float a0 = in_b[i * CD + su];
            float a1 = in_b[i * CD + su + 4];
#pragma unroll 16
            for (int k = 0; k < D; ++k) {
                float r = res[k * TBLK + c];
                a0 = fmaf(w0[k], r, a0);
                a1 = fmaf(w1[k], r, a1);
            }
            zen[c * 9 + su]     = a0;
            zen[c * 9 + su + 4] = a1;
            o_lat[(size_t)b * (NCB * CD) * T + (size_t)(i * CD + su) * T + t]     = a0;
            o_lat[(size_t)b * (NCB * CD) * T + (size_t)(i * CD + su + 4) * T + t] = a1;
        }
        __syncthreads();

        // ---- split phase: normalize en, 3-term bf16 split into es ---------
        if (tid < 64) {
            float v[CD]; float n2 = 0.f;
#pragma unroll
            for (int j = 0; j < CD; ++j) { v[j] = zen[tid * 9 + j]; n2 = fmaf(v[j], v[j], n2); }
            float inv = 1.0f / fmaxf(sqrtf(n2), 1e-12f);
            unsigned pk[3][4];
#pragma unroll
            for (int w = 0; w < 4; ++w) {
                float x0 = v[2 * w] * inv, x1 = v[2 * w + 1] * inv;
                unsigned short a0 = f2bf(x0); float r0 = x0 - bf2f(a0);
                unsigned short a1 = f2bf(r0); float q0 = r0 - bf2f(a1);
                unsigned short a2 = f2bf(q0);
                unsigned short b0 = f2bf(x1); float r1 = x1 - bf2f(b0);
                unsigned short b1 = f2bf(r1); float q1 = r1 - bf2f(b1);
                unsigned short b2 = f2bf(q1);
                pk[0][w] = (unsigned)a0 | ((unsigned)b0 << 16);
                pk[1][w] = (unsigned)a1 | ((unsigned)b1 << 16);
                pk[2][w] = (unsigned)a2 | ((unsigned)b2 << 16);
            }
            uint4* ep = reinterpret_cast<uint4*>(&es[(size_t)tid * 12]);
            ep[0] = make_uint4(pk[0][0], pk[0][1], pk[0][2], pk[0][3]);
            ep[1] = make_uint4(pk[1][0], pk[1][1], pk[1][2], pk[1][3]);
            ep[2] = make_uint4(pk[2][0], pk[2][1], pk[2][2], pk[2][3]);
        }
        __syncthreads();

        // ---- build B fragments (en side) from es --------------------------
        // B-frag layout (pinned by m162 tr_b16 + m89 D-layout):
        //   n = lane&15, k = 16*(j>>2) + (lane>>4)*4 + (j&3)  per K-half
        // kh0: j0-3 -> e0, j4-7 -> e[h>>1]; kh1: both halves -> e[1+(h>>1)]
        bf16x8 bfrag[4][2];
        {
            const int dwo = (h & 1) * 2;
            const int tA  = h >> 1;
            const int tB  = 1 + (h >> 1);
#pragma unroll
            for (int pt = 0; pt < 4; ++pt) {
                const int col = pt * 16 + nl;
                uint2 lo0 = *reinterpret_cast<const uint2*>(&es[col * 12 + 0 * 4 + dwo]);
                uint2 hi0 = *reinterpret_cast<const uint2*>(&es[col * 12 + tA * 4 + dwo]);
                uint2 lh1 = *reinterpret_cast<const uint2*>(&es[col * 12 + tB * 4 + dwo]);
                uint4 t0v = make_uint4(lo0.x, lo0.y, hi0.x, hi0.y);
                uint4 t1v = make_uint4(lh1.x, lh1.y, lh1.x, lh1.y);
                bfrag[pt][0] = *reinterpret_cast<bf16x8*>(&t0v);
                bfrag[pt][1] = *reinterpret_cast<bf16x8*>(&t1v);
            }
        }

        // ---- MFMA search: wave su owns entries [su*256, su*256+256) -------
        float best[4] = {-3.0e38f, -3.0e38f, -3.0e38f, -3.0e38f};
        int   bidx[4] = {0, 0, 0, 0};
        {
            const uint4* Ab = reinterpret_cast<const uint4*>(afr)
                              + ((size_t)(i * 64 + su * 16) * 2) * 64 + l;
            const f32x4* Hb = reinterpret_cast<const f32x4*>(h2m)
                              + (size_t)(i * 64 + su * 16) * 64 + l;
            int eb = (su * 16) * 16 + h * 4;   // entry index base for reg 0
#pragma unroll 2
            for (int e16 = 0; e16 < 16; ++e16) {
                uint4 ua0 = Ab[0];     // kh0 A-fragment (16B/lane, coalesced)
                uint4 ua1 = Ab[64];    // kh1 A-fragment
                f32x4 hv  = Hb[0];     // exact -h2 as C-init
                bf16x8 a0 = *reinterpret_cast<bf16x8*>(&ua0);
                bf16x8 a1 = *reinterpret_cast<bf16x8*>(&ua1);
#pragma unroll
                for (int pt = 0; pt < 4; ++pt) {
                    f32x4 acc = __builtin_amdgcn_mfma_f32_16x16x32_bf16(a0, bfrag[pt][0], hv, 0, 0, 0);
                    acc = __builtin_amdgcn_mfma_f32_16x16x32_bf16(a1, bfrag[pt][1], acc, 0, 0, 0);
#pragma unroll
                    for (int r = 0; r < 4; ++r) {
                        float sc = acc[r];
                        if (sc > best[pt]) { best[pt] = sc; bidx[pt] = eb + r; }  // strict > : first idx (ascending per lane)
                    }
                }
                Ab += 128; Hb += 64; eb += 16;
            }
        }

        // wave-internal merge across the 4 row-groups (lanes l^16, l^32)
        // rows interleave across groups -> explicit first-index tie-break
#pragma unroll
        for (int off = 16; off <= 32; off <<= 1) {
#pragma unroll
            for (int pt = 0; pt < 4; ++pt) {
                float ob = __shfl_xor(best[pt], off, 64);
                int   oi = __shfl_xor(bidx[pt], off, 64);
                bool tk = (ob > best[pt]) || (ob == best[pt] && oi < bidx[pt]);
                if (tk) { best[pt] = ob; bidx[pt] = oi; }
            }
        }
        if (l < 16) {
#pragma unroll
            for (int pt = 0; pt < 4; ++pt) {
                redS[su * 64 + pt * 16 + l] = best[pt];
                redI[su * 64 + pt * 16 + l] = bidx[pt];
            }
        }
        __syncthreads();

        // final reduce across 4 waves (ascending wave = ascending entry range)
        float bsc = redS[c];
        int   bi  = redI[c];
#pragma unroll
        for (int ww = 1; ww < 4; ++ww) {
            float v2 = redS[ww * TBLK + c];
            int   vi = redI[ww * TBLK + c];
            if (v2 > bsc) { bsc = v2; bi = vi; }
        }
        if (s == 0) o_codes[(size_t)b * NCB * T + (size_t)i * T + t] = (float)bi;

        // straight-through zq = z_e + (cb_raw[idx] - z_e); loss (once per column)
        float zq[CD];
        {
            float zer[CD];
#pragma unroll
            for (int j = 0; j < CD; ++j) zer[j] = zen[c * 9 + j];
            const float4* cr4 = (const float4*)(codebook + ((size_t)i * CB + bi) * CD);
            float4 qa = cr4[0], qb = cr4[1];
            float cv[CD] = {qa.x, qa.y, qa.z, qa.w, qb.x, qb.y, qb.z, qb.w};
#pragma unroll
            for (int j = 0; j < CD; ++j) {
                zq[j] = zer[j] + (cv[j] - zer[j]);
                if (s == 0) { float dd = cv[j] - zer[j]; loss_local = fmaf(dd, dd, loss_local); }
            }
        }

        // out_proj + residual update: wave owns rows d in [su*32, su*32+32)
        {
            const float* ow = out_w + (size_t)(i * D + su * 32) * CD;  // uniform
            const float* ob = out_b + i * D + su * 32;                 // uniform
#pragma unroll 4
            for (int k = 0; k < 32; ++k) {
                float acc = ob[k];
#pragma unroll
                for (int j = 0; j < CD; ++j) acc = fmaf(ow[k * CD + j], zq[j], acc);
                res[(su * 32 + k) * TBLK + c] -= acc;   // unique owner per (d,c)
            }
        }
    }
    __syncthreads();

    // ---------------- final: z_q = z - residual (recompute z) --------------
    {
        const float* xm = x     + (size_t)b * 2 * D * T + (size_t)(su * 32) * T + t;
        const float* xs = xm    + (size_t)D * T;
        const float* nz = noise + (size_t)b * D * T     + (size_t)(su * 32) * T + t;
        float*       oq = o_zq  + (size_t)b * D * T     + (size_t)(su * 32) * T + t;
#pragma unroll 8
        for (int k = 0; k < 32; ++k) {
            float m  = xm[(size_t)k * T];
            float sc = xs[(size_t)k * T];
            float nv = nz[(size_t)k * T];
            float sp = fmaxf(sc, 0.f) + log1pf(expf(-fabsf(sc)));
            float sd = sp + 1e-4f;
            float zv = fmaf(nv, sd, m);
            oq[(size_t)k * T] = zv - res[(su * 32 + k) * TBLK + c];
        }
    }

    // ---------------- scalar reductions ------------------------------------
    float v = kl_local;
#pragma unroll
    for (int o = 32; o > 0; o >>= 1) v += __shfl_down(v, o, 64);
    float w2 = loss_local;
#pragma unroll
    for (int o = 32; o > 0; o >>= 1) w2 += __shfl_down(w2, o, 64);
    if ((tid & 63) == 0) { redw[s] = v; redw[4 + s] = w2; }
    __syncthreads();
    if (tid == 0) {
        float ks = redw[0] + redw[1] + redw[2] + redw[3];
        float ls = redw[4] + redw[5] + redw[6] + redw[7];
        atomicAdd(&o_scal[0], ks * (1.0f / 65536.0f));               // kl: /(B*T)
        float lsn = ls * (1.0f / (524288.0f * 9.0f));                // /(B*8*T)/NCB
        atomicAdd(&o_scal[1], lsn);                                  // commitment
        atomicAdd(&o_scal[2], lsn);                                  // codebook (identical in eval)
    }
}

extern "C" void kernel_launch(void* const* d_in, const int* in_sizes, int n_in,
                              void* d_out, int out_size, void* d_ws, size_t ws_size,
                              hipStream_t stream) {
    const float* x        = (const float*)d_in[0];
    const float* noise    = (const float*)d_in[1];
    const float* in_w     = (const float*)d_in[2];
    const float* in_b     = (const float*)d_in[3];
    const float* codebook = (const float*)d_in[4];
    const float* out_w    = (const float*)d_in[5];
    const float* out_b    = (const float*)d_in[6];

    float* out     = (float*)d_out;
    float* o_zq    = out + OFF_ZQ;
    float* o_scal  = out + OFF_SCAL;
    float* o_codes = out + OFF_CODES;
    float* o_lat   = out + OFF_LAT;

    // workspace: A-side MFMA fragments (bf16 split) + exact -h2 in D-layout
    unsigned* afr = (unsigned*)d_ws;
    float*    h2m = (float*)(afr + AFR_U32);

    prep_kernel<<<(NCB * CB + 255) / 256, 256, 0, stream>>>(codebook, afr, h2m, o_scal);

    dim3 grid(BB * (T / TBLK));  // 16 * 64 = 1024 blocks
    rvq_kernel<<<grid, NTHR, 0, stream>>>(x, noise, in_w, in_b, codebook, out_w, out_b,
                                          afr, h2m, o_zq, o_scal, o_codes, o_lat);
}

// Round 3
// 388.971 us; speedup vs baseline: 1.2013x; 1.0131x over previous
//
#include <hip/hip_runtime.h>
#include <cstdint>
#include <cstddef>

// Problem constants (DAC RVQ VAE bottleneck)
constexpr int T   = 4096;
constexpr int BB  = 16;
constexpr int D   = 128;   // INPUT_DIM
constexpr int CB  = 1024;  // CODEBOOK_SIZE
constexpr int CD  = 8;     // CODEBOOK_DIM
constexpr int NCB = 9;     // N_CODEBOOKS

constexpr int TBLK = 64;   // columns (t positions) per block
constexpr int NTHR = 256;  // 4 waves
constexpr int ZLS  = 66;   // Zl row stride (bank-conflict pad)

// Output layout (flat f32 concat, reference return order):
//   z_q [16*128*4096] | kl [1] | commit [1] | cbloss [1] | codes [16*9*4096] | latents [16*72*4096]
constexpr size_t OFF_ZQ    = 0;
constexpr size_t OFF_SCAL  = (size_t)BB * D * T;               // 8388608
constexpr size_t OFF_CODES = OFF_SCAL + 3;                     // 8388611
constexpr size_t OFF_LAT   = OFF_CODES + (size_t)BB * NCB * T; // 8978435

// Workspace layout (units: u32/f32), sequential:
//   afr [294912 u32] : search A-frags (codebook 3-term split)
//   h2c [9216 f32]   : -0.5*||cbn||^2 compact (per entry)
//   afw [30720 u32]  : Z-precompute A-frags (Wall 3-term split)
//   CMt [5184 f32]   : CM[j][72][8] = in_w_flat · out_w_j
//   obs [128 f32]    : sum_i out_b[i][.]
//   bef [72 f32]     : beff[row] = in_b[row] - sum_{j<i(row)} in_w[row]·out_b[j]
//   OPt [1179648 f32]: OP[i][e][128] = out_w_i · cb_i[e]
constexpr size_t AFR_U32 = (size_t)NCB * 64 * 2 * 64 * 4;  // 294912
constexpr size_t H2C_F32 = (size_t)NCB * CB;               // 9216
constexpr size_t AFW_U32 = (size_t)2 * 6 * 2 * 5 * 64 * 4; // 30720
constexpr size_t CM_F32  = (size_t)NCB * 72 * 8;           // 5184
constexpr size_t OBS_F32 = 128;
constexpr size_t BEF_F32 = 72;
constexpr size_t OP_F32  = (size_t)NCB * CB * D;           // 1179648

typedef short bf16x8 __attribute__((ext_vector_type(8)));
typedef float f32x4  __attribute__((ext_vector_type(4)));

__device__ __forceinline__ unsigned short f2bf(float f) {
    unsigned u = __float_as_uint(f);
    return (unsigned short)((u + (((u >> 16) & 1u) + 0x7FFFu)) >> 16);  // RNE
}
__device__ __forceinline__ float bf2f(unsigned short b) {
    return __uint_as_float((unsigned)b << 16);
}

// Z-precompute term pairs: (wA term, zB term). Dropped (1,2),(2,1),(2,2) ~2^-27/prod.
constexpr int PAIR_A[6] = {0, 0, 1, 1, 2, 0};
constexpr int PAIR_B[6] = {0, 1, 0, 1, 0, 2};

__device__ __forceinline__ unsigned short splitterm(float xv, int term) {
    unsigned short t0 = f2bf(xv); if (term == 0) return t0;
    float r1 = xv - bf2f(t0);
    unsigned short t1 = f2bf(r1); if (term == 1) return t1;
    float r2 = r1 - bf2f(t1);
    return f2bf(r2);
}

// ---------------------------------------------------------------------------
// Prep (single launch, role by flat id):
//  [0, 9216)              : search afr + h2c + scal zero
//  [9216, 18432)          : OP rows
//  [18432, 19080)         : CM[j][r][8]
//  [19080, 19208)         : obs
//  [19208, 19280)         : beff (bias with folded out_b corrections)
//  [19280, 26960)         : afw (Wall split A-frags)
// ---------------------------------------------------------------------------
__global__ void prep_kernel(const float* __restrict__ codebook,
                            const float* __restrict__ in_w,
                            const float* __restrict__ in_b,
                            const float* __restrict__ out_w,
                            const float* __restrict__ out_b,
                            unsigned* __restrict__ afr,
                            float* __restrict__ h2c,
                            unsigned* __restrict__ afw,
                            float* __restrict__ CMt,
                            float* __restrict__ obs,
                            float* __restrict__ bef,
                            float* __restrict__ OPt,
                            float* __restrict__ scal) {
    const int gid = blockIdx.x * blockDim.x + threadIdx.x;
    if (gid == 0) { scal[0] = 0.f; scal[1] = 0.f; scal[2] = 0.f; }

    if (gid < NCB * CB) {
        // ---- search A-frags (verbatim round-1 math) + compact h2c ----
        const int e  = gid;
        const int i  = e >> 10;
        const int en = e & 1023;
        const int et = en >> 4;
        const int m  = en & 15;

        float v[CD]; float s2 = 0.f;
#pragma unroll
        for (int j = 0; j < CD; ++j) { v[j] = codebook[(size_t)e * CD + j]; s2 = fmaf(v[j], v[j], s2); }
        float inv = 1.0f / fmaxf(sqrtf(s2), 1e-12f);
        float cn[CD]; float c2 = 0.f;
#pragma unroll
        for (int j = 0; j < CD; ++j) { cn[j] = v[j] * inv; c2 = fmaf(cn[j], cn[j], c2); }
        h2c[e] = -0.5f * c2;  // exact fp32, negated (MFMA C-init)

        unsigned pk[3][4];
#pragma unroll
        for (int w = 0; w < 4; ++w) {
            float x0 = cn[2 * w], x1 = cn[2 * w + 1];
            unsigned short a0 = f2bf(x0); float r0 = x0 - bf2f(a0);
            unsigned short a1 = f2bf(r0); float q0 = r0 - bf2f(a1);
            unsigned short a2 = f2bf(q0);
            unsigned short b0 = f2bf(x1); float r1 = x1 - bf2f(b0);
            unsigned short b1 = f2bf(r1); float q1 = r1 - bf2f(b1);
            unsigned short b2 = f2bf(q1);
            pk[0][w] = (unsigned)a0 | ((unsigned)b0 << 16);
            pk[1][w] = (unsigned)a1 | ((unsigned)b1 << 16);
            pk[2][w] = (unsigned)a2 | ((unsigned)b2 << 16);
        }
        const int At[8] = {0, 1, 2, 0, 1, 0, 2, 1};
#pragma unroll
        for (int kh = 0; kh < 2; ++kh) {
#pragma unroll
            for (int h = 0; h < 4; ++h) {
                int A1 = At[kh * 4 + (h >> 1)];
                int A2 = At[kh * 4 + 2 + (h >> 1)];
                int dw = (h & 1) * 2;
                size_t off = ((((size_t)i * 64 + et) * 2 + kh) * 64 + (h * 16 + m)) * 4;
                afr[off + 0] = pk[A1][dw];
                afr[off + 1] = pk[A1][dw + 1];
                afr[off + 2] = pk[A2][dw];
                afr[off + 3] = pk[A2][dw + 1];
            }
        }
        return;
    }
    if (gid < 2 * NCB * CB) {
        // ---- OP[i][e][r] = sum_d out_w[i][r][d] * cb[i][e][d] (raw codebook) ----
        const int e = gid - NCB * CB;
        const int i = e >> 10;
        float cv[CD];
#pragma unroll
        for (int d = 0; d < CD; ++d) cv[d] = codebook[(size_t)e * CD + d];
        const float* ow = out_w + (size_t)i * D * CD;
        float* dst = OPt + (size_t)e * D;
        for (int r = 0; r < D; ++r) {
            float a = 0.f;
#pragma unroll
            for (int d = 0; d < CD; ++d) a = fmaf(ow[r * CD + d], cv[d], a);
            dst[r] = a;
        }
        return;
    }
    if (gid < 2 * NCB * CB + NCB * 72) {
        // ---- CM[j][r][d] = sum_k in_w_flat[r][k] * out_w[j][k][d] ----
        const int idx = gid - 2 * NCB * CB;
        const int j = idx / 72, r = idx - j * 72;
        const float* wi = in_w + (size_t)r * D;         // in_w flat [72][128]
        const float* ow = out_w + (size_t)j * D * CD;
        float a[CD];
#pragma unroll
        for (int d = 0; d < CD; ++d) a[d] = 0.f;
        for (int k = 0; k < D; ++k) {
            float w = wi[k];
#pragma unroll
            for (int d = 0; d < CD; ++d) a[d] = fmaf(w, ow[k * CD + d], a[d]);
        }
#pragma unroll
        for (int d = 0; d < CD; ++d) CMt[((size_t)j * 72 + r) * CD + d] = a[d];
        return;
    }
    if (gid < 2 * NCB * CB + NCB * 72 + 128) {
        const int r = gid - (2 * NCB * CB + NCB * 72);
        float a = 0.f;
        for (int i = 0; i < NCB; ++i) a += out_b[(size_t)i * D + r];
        obs[r] = a;
        return;
    }
    if (gid < 2 * NCB * CB + NCB * 72 + 128 + 72) {
        // ---- beff[row] = in_b[row] - sum_{j < row>>3} sum_k in_w[row][k]*out_b[j][k]
        const int row = gid - (2 * NCB * CB + NCB * 72 + 128);
        const int ic  = row >> 3;
        const float* wi = in_w + (size_t)row * D;
        float a = in_b[row];
        for (int j = 0; j < ic; ++j) {
            const float* ob = out_b + (size_t)j * D;
            float s = 0.f;
            for (int k = 0; k < D; ++k) s = fmaf(wi[k], ob[k], s);
            a -= s;
        }
        bef[row] = a;
        return;
    }
    if (gid < 2 * NCB * CB + NCB * 72 + 128 + 72 + 7680) {
        // ---- afw: Z-precompute A-frags. idx -> (P,p,kq,mt,lane) ----
        int idx = gid - (2 * NCB * CB + NCB * 72 + 128 + 72);
        const int lane = idx & 63; idx >>= 6;
        const int mt = idx % 5; idx /= 5;
        const int kq = idx & 1; idx >>= 1;
        const int p  = idx % 6;
        const int P  = idx / 6;
        const int h  = lane >> 4, m = lane & 15;
        const int row = mt * 16 + m;
        const int term = PAIR_A[p];
        const int D0 = P * 64 + kq * 32 + h * 4;
        const int doff[4][2] = {{0, 1}, {2, 3}, {16, 17}, {18, 19}};
        unsigned wv[4];
#pragma unroll
        for (int w = 0; w < 4; ++w) {
            unsigned short lo = 0, hi = 0;
            if (row < 72) {
                lo = splitterm(in_w[(size_t)row * D + D0 + doff[w][0]], term);
                hi = splitterm(in_w[(size_t)row * D + D0 + doff[w][1]], term);
            }
            wv[w] = (unsigned)lo | ((unsigned)hi << 16);
        }
        *reinterpret_cast<uint4*>(afw + ((size_t)(((P * 6 + p) * 2 + kq) * 5 + mt) * 64 + lane) * 4)
            = make_uint4(wv[0], wv[1], wv[2], wv[3]);
        return;
    }
}

// ---------------------------------------------------------------------------
// Main fused kernel.
//   Phase Z: z (vae) -> 3-term split -> MFMA Z = Wall*z + beff
//   Loop i: es split from Zl rows; MFMA search; corrections Z -= CM*zq; codes.
//   Final:  z_q[r][c] = obs[r] + sum_i OP[i][code_i(c)][r]  (gather)
// ---------------------------------------------------------------------------
__global__ __launch_bounds__(NTHR, 4)
void rvq_kernel(const float* __restrict__ x,
                const float* __restrict__ noise,
                const float* __restrict__ codebook,
                const unsigned* __restrict__ afr,
                const float* __restrict__ h2c,
                const unsigned* __restrict__ afw,
                const float* __restrict__ CMt,
                const float* __restrict__ obs,
                const float* __restrict__ bef,
                const float* __restrict__ OPt,
                float* __restrict__ o_zq,
                float* __restrict__ o_scal,
                float* __restrict__ o_codes,
                float* __restrict__ o_lat) {
    __shared__ char     zbuf[24576];        // union: zs (24KB) then Zl (80x66 f32, 21.1KB)
    __shared__ unsigned es[TBLK * 12];      // split en: [col][3 terms][4xu32] (3 KB)
    __shared__ float    redS[4 * TBLK];     // per-wave best score (1 KB)
    __shared__ int      redI[4 * TBLK];     // per-wave best index (1 KB)
    __shared__ int      cidx[NCB * TBLK];   // selected codes (2.25 KB)
    __shared__ float    redw[8];

    uint2* zs = reinterpret_cast<uint2*>(zbuf);   // [(term*16+db)*64 + col]
    float* Zl = reinterpret_cast<float*>(zbuf);   // [row*ZLS + col]

    const int tid = threadIdx.x;
    const int c   = tid & 63;            // column for col-parallel phases
    const int s   = tid >> 6;            // wave id
    const int su  = __builtin_amdgcn_readfirstlane(s);
    const int b   = blockIdx.x >> 6;
    const int t0  = (blockIdx.x & 63) << 6;
    const int t   = t0 + c;

    const int l  = tid & 63;             // lane
    const int h  = l >> 4;               // 16-lane group
    const int nl = l & 15;               // position-within-tile

    // ================= Phase Z: Z = Wall * z + beff (MFMA) =================
    float kl_local = 0.f;
    f32x4 acc[5];
#pragma unroll
    for (int mt = 0; mt < 5; ++mt) {
        int row0 = mt * 16 + h * 4;
        if (row0 < 72) acc[mt] = *reinterpret_cast<const f32x4*>(bef + row0);
        else           acc[mt] = f32x4{0.f, 0.f, 0.f, 0.f};
    }

#pragma unroll 1
    for (int P = 0; P < 2; ++P) {
        // ---- produce: rows P*64 + su*16 .. +15, col c ----
        {
            const int r0 = P * 64 + su * 16;
            const float* xm = x     + (size_t)b * 2 * D * T + (size_t)r0 * T + t;
            const float* xs = xm    + (size_t)D * T;
            const float* nz = noise + (size_t)b * D * T     + (size_t)r0 * T + t;
            float zrow[16];
#pragma unroll
            for (int k = 0; k < 16; ++k) {
                float m  = xm[(size_t)k * T];
                float sc = xs[(size_t)k * T];
                float nv = nz[(size_t)k * T];
                float sp  = fmaxf(sc, 0.f) + log1pf(expf(-fabsf(sc)));  // softplus
                float sd  = sp + 1e-4f;
                float var = sd * sd;
                zrow[k]   = fmaf(nv, sd, m);
                kl_local += m * m + var - logf(var) - 1.0f;
            }
#pragma unroll
            for (int db = 0; db < 4; ++db) {
                unsigned w[3][2];
#pragma unroll
                for (int half = 0; half < 2; ++half) {
                    float x0 = zrow[db * 4 + half * 2], x1 = zrow[db * 4 + half * 2 + 1];
                    unsigned short a0 = f2bf(x0); float r1 = x0 - bf2f(a0);
                    unsigned short a1 = f2bf(r1); float r2 = r1 - bf2f(a1);
                    unsigned short a2 = f2bf(r2);
                    unsigned short b0 = f2bf(x1); float s1v = x1 - bf2f(b0);
                    unsigned short b1 = f2bf(s1v); float s2v = s1v - bf2f(b1);
                    unsigned short b2 = f2bf(s2v);
                    w[0][half] = (unsigned)a0 | ((unsigned)b0 << 16);
                    w[1][half] = (unsigned)a1 | ((unsigned)b1 << 16);
                    w[2][half] = (unsigned)a2 | ((unsigned)b2 << 16);
                }
#pragma unroll
                for (int tt = 0; tt < 3; ++tt)
                    zs[(tt * 16 + su * 4 + db) * 64 + c] = make_uint2(w[tt][0], w[tt][1]);
            }
        }
        __syncthreads();
        // ---- consume: wave su = N-tile su (cols su*16+nl) ----
        {
            const int colB = su * 16 + nl;
#pragma unroll
            for (int p = 0; p < 6; ++p) {
#pragma unroll
                for (int kq = 0; kq < 2; ++kq) {
                    uint2 blo = zs[(PAIR_B[p] * 16 + kq * 8 + h) * 64 + colB];
                    uint2 bhi = zs[(PAIR_B[p] * 16 + kq * 8 + 4 + h) * 64 + colB];
                    uint4 bu = make_uint4(blo.x, blo.y, bhi.x, bhi.y);
                    bf16x8 bfr = *reinterpret_cast<bf16x8*>(&bu);
                    const uint4* Aw = reinterpret_cast<const uint4*>(afw)
                                      + (size_t)(((P * 6 + p) * 2 + kq) * 5) * 64 + l;
#pragma unroll
                    for (int mt = 0; mt < 5; ++mt) {
                        uint4 au = Aw[(size_t)mt * 64];
                        bf16x8 af = *reinterpret_cast<bf16x8*>(&au);
                        acc[mt] = __builtin_amdgcn_mfma_f32_16x16x32_bf16(af, bfr, acc[mt], 0, 0, 0);
                    }
                }
            }
        }
        __syncthreads();   // zs consumed (pass-1 rewrites / Zl overlays)
    }
    // ---- Zl store (overlays zs; all reads done) ----
#pragma unroll
    for (int mt = 0; mt < 5; ++mt)
#pragma unroll
        for (int r = 0; r < 4; ++r)
            Zl[(mt * 16 + h * 4 + r) * ZLS + su * 16 + nl] = acc[mt][r];

    float loss_local = 0.f;

    // ================= RVQ loop over 9 codebooks ===========================
    for (int i = 0; i < NCB; ++i) {
        __syncthreads();  // Zl rows current (corrections of i-1 done)

        // ---- split phase: normalize z_e, 3-term bf16 split into es --------
        if (tid < 64) {
            float v[CD]; float n2 = 0.f;
#pragma unroll
            for (int j = 0; j < CD; ++j) { v[j] = Zl[(i * CD + j) * ZLS + tid]; n2 = fmaf(v[j], v[j], n2); }
            float inv = 1.0f / fmaxf(sqrtf(n2), 1e-12f);
            unsigned pk[3][4];
#pragma unroll
            for (int w = 0; w < 4; ++w) {
                float x0 = v[2 * w] * inv, x1 = v[2 * w + 1] * inv;
                unsigned short a0 = f2bf(x0); float r0 = x0 - bf2f(a0);
                unsigned short a1 = f2bf(r0); float q0 = r0 - bf2f(a1);
                unsigned short a2 = f2bf(q0);
                unsigned short b0 = f2bf(x1); float r1 = x1 - bf2f(b0);
                unsigned short b1 = f2bf(r1); float q1 = r1 - bf2f(b1);
                unsigned short b2 = f2bf(q1);
                pk[0][w] = (unsigned)a0 | ((unsigned)b0 << 16);
                pk[1][w] = (unsigned)a1 | ((unsigned)b1 << 16);
                pk[2][w] = (unsigned)a2 | ((unsigned)b2 << 16);
            }
            uint4* ep = reinterpret_cast<uint4*>(&es[(size_t)tid * 12]);
            ep[0] = make_uint4(pk[0][0], pk[0][1], pk[0][2], pk[0][3]);
            ep[1] = make_uint4(pk[1][0], pk[1][1], pk[1][2], pk[1][3]);
            ep[2] = make_uint4(pk[2][0], pk[2][1], pk[2][2], pk[2][3]);
        }
        // ---- latents output (z_e rows final for this codebook) -----------
        {
            float la0 = Zl[(i * CD + su) * ZLS + c];
            float la1 = Zl[(i * CD + su + 4) * ZLS + c];
            o_lat[(size_t)b * (NCB * CD) * T + (size_t)(i * CD + su) * T + t]     = la0;
            o_lat[(size_t)b * (NCB * CD) * T + (size_t)(i * CD + su + 4) * T + t] = la1;
        }
        __syncthreads();

        // ---- build B fragments (en side) from es (round-1 verbatim) -------
        bf16x8 bfrag[4][2];
        {
            const int dwo = (h & 1) * 2;
            const int tA  = h >> 1;
            const int tB  = 1 + (h >> 1);
#pragma unroll
            for (int pt = 0; pt < 4; ++pt) {
                const int col = pt * 16 + nl;
                uint2 lo0 = *reinterpret_cast<const uint2*>(&es[col * 12 + 0 * 4 + dwo]);
                uint2 hi0 = *reinterpret_cast<const uint2*>(&es[col * 12 + tA * 4 + dwo]);
                uint2 lh1 = *reinterpret_cast<const uint2*>(&es[col * 12 + tB * 4 + dwo]);
                uint4 t0v = make_uint4(lo0.x, lo0.y, hi0.x, hi0.y);
                uint4 t1v = make_uint4(lh1.x, lh1.y, lh1.x, lh1.y);
                bfrag[pt][0] = *reinterpret_cast<bf16x8*>(&t0v);
                bfrag[pt][1] = *reinterpret_cast<bf16x8*>(&t1v);
            }
        }

        // ---- MFMA search: wave su owns entries [su*256, su*256+256) -------
        float best[4] = {-3.0e38f, -3.0e38f, -3.0e38f, -3.0e38f};
        int   bidx[4] = {0, 0, 0, 0};
        {
            const uint4* Ab = reinterpret_cast<const uint4*>(afr)
                              + ((size_t)(i * 64 + su * 16) * 2) * 64 + l;
            const f32x4* Hb = reinterpret_cast<const f32x4*>(h2c + (size_t)i * CB + su * 256);
            int eb = (su * 16) * 16 + h * 4;
#pragma unroll 2
            for (int e16 = 0; e16 < 16; ++e16) {
                uint4 ua0 = Ab[0];
                uint4 ua1 = Ab[64];
                f32x4 hv  = Hb[e16 * 4 + h];   // exact -h2 as C-init (compact, h-uniform)
                bf16x8 a0 = *reinterpret_cast<bf16x8*>(&ua0);
                bf16x8 a1 = *reinterpret_cast<bf16x8*>(&ua1);
#pragma unroll
                for (int pt = 0; pt < 4; ++pt) {
                    f32x4 accd = __builtin_amdgcn_mfma_f32_16x16x32_bf16(a0, bfrag[pt][0], hv, 0, 0, 0);
                    accd = __builtin_amdgcn_mfma_f32_16x16x32_bf16(a1, bfrag[pt][1], accd, 0, 0, 0);
#pragma unroll
                    for (int r = 0; r < 4; ++r) {
                        float sc = accd[r];
                        if (sc > best[pt]) { best[pt] = sc; bidx[pt] = eb + r; }  // strict >: first idx
                    }
                }
                Ab += 128; eb += 16;
            }
        }

        // wave-internal merge (explicit first-index tie-break)
#pragma unroll
        for (int off = 16; off <= 32; off <<= 1) {
#pragma unroll
            for (int pt = 0; pt < 4; ++pt) {
                float ob = __shfl_xor(best[pt], off, 64);
                int   oi = __shfl_xor(bidx[pt], off, 64);
                bool tk = (ob > best[pt]) || (ob == best[pt] && oi < bidx[pt]);
                if (tk) { best[pt] = ob; bidx[pt] = oi; }
            }
        }
        if (l < 16) {
#pragma unroll
            for (int pt = 0; pt < 4; ++pt) {
                redS[su * 64 + pt * 16 + l] = best[pt];
                redI[su * 64 + pt * 16 + l] = bidx[pt];
            }
        }
        __syncthreads();

        // final reduce across 4 waves (ascending wave = ascending entry range)
        float bsc = redS[c];
        int   bi  = redI[c];
#pragma unroll
        for (int ww = 1; ww < 4; ++ww) {
            float v2 = redS[ww * TBLK + c];
            int   vi = redI[ww * TBLK + c];
            if (v2 > bsc) { bsc = v2; bi = vi; }
        }
        cidx[i * TBLK + c] = bi;   // benign multi-write of identical value
        if (s == 0) o_codes[(size_t)b * NCB * T + (size_t)i * T + t] = (float)bi;

        // gather raw codebook row; loss (once per column)
        float cv[CD];
        {
            const float4* cr4 = (const float4*)(codebook + ((size_t)i * CB + bi) * CD);
            float4 qa = cr4[0], qb = cr4[1];
            cv[0] = qa.x; cv[1] = qa.y; cv[2] = qa.z; cv[3] = qa.w;
            cv[4] = qb.x; cv[5] = qb.y; cv[6] = qb.z; cv[7] = qb.w;
            if (s == 0) {
#pragma unroll
                for (int j = 0; j < CD; ++j) {
                    float dd = cv[j] - Zl[(i * CD + j) * ZLS + c];
                    loss_local = fmaf(dd, dd, loss_local);
                }
            }
        }

        // ---- corrections: Z[row] -= CM[i][row] . cv, rows (i+1)*8 .. 71 ---
        {
            const int nf = 64 - 8 * i;
            for (int rr = su; rr < nf; rr += 4) {
                const int row = (i + 1) * 8 + rr;
                float zv = Zl[row * ZLS + c];
                const float* cm = CMt + ((size_t)i * 72 + row) * CD;
#pragma unroll
                for (int d2 = 0; d2 < CD; ++d2) zv = fmaf(-cm[d2], cv[d2], zv);
                Zl[row * ZLS + c] = zv;
            }
        }
    }
    __syncthreads();  // cidx complete

    // ================= final: z_q = obs + sum_i OP[i][code_i] ==============
    {
        f32x4 oa[8];
#pragma unroll
        for (int kb = 0; kb < 8; ++kb)
            oa[kb] = *reinterpret_cast<const f32x4*>(obs + su * 32 + kb * 4);
#pragma unroll
        for (int i2 = 0; i2 < NCB; ++i2) {
            int code = cidx[i2 * TBLK + c];
            const f32x4* op = reinterpret_cast<const f32x4*>(OPt + ((size_t)(i2 * CB + code)) * D + su * 32);
#pragma unroll
            for (int kb = 0; kb < 8; ++kb) oa[kb] += op[kb];
        }
        float* oq = o_zq + (size_t)b * D * T + (size_t)(su * 32) * T + t;
#pragma unroll
        for (int kb = 0; kb < 8; ++kb)
#pragma unroll
            for (int r = 0; r < 4; ++r)
                oq[(size_t)(kb * 4 + r) * T] = oa[kb][r];
    }

    // ================= scalar reductions ===================================
    float v = kl_local;
#pragma unroll
    for (int o = 32; o > 0; o >>= 1) v += __shfl_down(v, o, 64);
    float w2 = loss_local;
#pragma unroll
    for (int o = 32; o > 0; o >>= 1) w2 += __shfl_down(w2, o, 64);
    if ((tid & 63) == 0) { redw[s] = v; redw[4 + s] = w2; }
    __syncthreads();
    if (tid == 0) {
        float ks = redw[0] + redw[1] + redw[2] + redw[3];
        float ls = redw[4] + redw[5] + redw[6] + redw[7];
        atomicAdd(&o_scal[0], ks * (1.0f / 65536.0f));               // kl: /(B*T)
        float lsn = ls * (1.0f / (524288.0f * 9.0f));                // /(B*8*T)/NCB
        atomicAdd(&o_scal[1], lsn);                                  // commitment
        atomicAdd(&o_scal[2], lsn);                                  // codebook (identical in eval)
    }
}

extern "C" void kernel_launch(void* const* d_in, const int* in_sizes, int n_in,
                              void* d_out, int out_size, void* d_ws, size_t ws_size,
                              hipStream_t stream) {
    const float* x        = (const float*)d_in[0];
    const float* noise    = (const float*)d_in[1];
    const float* in_w     = (const float*)d_in[2];
    const float* in_b     = (const float*)d_in[3];
    const float* codebook = (const float*)d_in[4];
    const float* out_w    = (const float*)d_in[5];
    const float* out_b    = (const float*)d_in[6];

    float* out     = (float*)d_out;
    float* o_zq    = out + OFF_ZQ;
    float* o_scal  = out + OFF_SCAL;
    float* o_codes = out + OFF_CODES;
    float* o_lat   = out + OFF_LAT;

    unsigned* afr = (unsigned*)d_ws;
    float*    h2c = (float*)(afr + AFR_U32);
    unsigned* afw = (unsigned*)(h2c + H2C_F32);
    float*    CMt = (float*)(afw + AFW_U32);
    float*    obs = CMt + CM_F32;
    float*    bef = obs + OBS_F32;
    float*    OPt = bef + BEF_F32;

    const int prep_total = 2 * NCB * CB + NCB * 72 + 128 + 72 + 7680;  // 26960
    prep_kernel<<<(prep_total + 255) / 256, 256, 0, stream>>>(
        codebook, in_w, in_b, out_w, out_b, afr, h2c, afw, CMt, obs, bef, OPt, o_scal);

    dim3 grid(BB * (T / TBLK));  // 16 * 64 = 1024 blocks
    rvq_kernel<<<grid, NTHR, 0, stream>>>(x, noise, codebook,
                                          afr, h2c, afw, CMt, obs, bef, OPt,
                                          o_zq, o_scal, o_codes, o_lat);
}